// Round 3
// baseline (175.549 us; speedup 1.0000x reference)
//
#include <hip/hip_runtime.h>
#include <hip/hip_fp16.h>
#include <stdint.h>

#define BATCH 4096
#define N_IN  512
#define H1    1536
#define H2    1536
#define N_OUT 512
#define FAN   32
#define E0 (H1 * FAN)
#define E1 (H2 * FAN)
#define E2 (N_OUT * FAN)
#define ETOT (E0 + E1 + E2)
#define NNODES (H1 + H2 + N_OUT)   // 3584 non-input nodes
#define MAXDEG 128                 // slot capacity; Poisson(32) max ~54, 128 = guard-free staging

// ---- workspace layout (bytes), total 37,238,784 (< 38.7 MB proven safe) ----
// nv    : 4096 rows x 4096 cols x 2B (fp16) = 33,554,432
//         rows 0..511 = x^T, 512..2047 = h1, 2048..3583 = h2, 3584..4095 = out^T
// edges : slotted [NNODES][MAXDEG] int2 = 3,670,016
// cnt   : NNODES ints = 14,336
#define OFF_EDGES 33554432
#define OFF_CNT   (OFF_EDGES + NNODES * MAXDEG * 8)

// ---------- x [B, N_IN] fp32 -> rows 0..511 of nv (fp16, [node][batch]) ----------
__global__ __launch_bounds__(256) void k_transpose_in(const float* __restrict__ x,
                                                      __half* __restrict__ xT) {
    __shared__ float tile[32][33];
    const int tx = threadIdx.x, ty = threadIdx.y;   // 32 x 8
    const int n0 = blockIdx.x * 32;                 // node base
    const int b0 = blockIdx.y * 32;                 // batch base
#pragma unroll
    for (int k = 0; k < 32; k += 8)
        tile[ty + k][tx] = x[(size_t)(b0 + ty + k) * N_IN + (n0 + tx)];
    __syncthreads();
#pragma unroll
    for (int k = 0; k < 32; k += 8)
        xT[(size_t)(n0 + ty + k) * BATCH + (b0 + tx)] = __float2half_rn(tile[tx][ty + k]);
}

// ---------- slotted edge-table fill: one pass, no scan ----------
__global__ __launch_bounds__(256) void k_fill(const int* __restrict__ s0, const int* __restrict__ d0, const float* __restrict__ w0,
                                              const int* __restrict__ s1, const int* __restrict__ d1, const float* __restrict__ w1,
                                              const int* __restrict__ s2, const int* __restrict__ d2, const float* __restrict__ w2,
                                              int* __restrict__ cnt, int2* __restrict__ edges) {
    const int e = blockIdx.x * 256 + threadIdx.x;
    int src, node; float w;
    if (e < E0)           { src = s0[e];          node = d0[e];                w = w0[e]; }
    else if (e < E0 + E1) { int i = e - E0;       src = s1[i]; node = H1 + d1[i];        w = w1[i]; }
    else                  { int i = e - E0 - E1;  src = s2[i]; node = H1 + H2 + d2[i];   w = w2[i]; }
    const int pos = atomicAdd(&cnt[node], 1);
    if (pos < MAXDEG) edges[node * MAXDEG + pos] = make_int2(src, __float_as_int(w));
}

// ---------- level kernel: 256 thr = 4 waves, wave = one node, 256-col tiles ----------
// R1 (deeper ILP) and R2 (more TLP) were both null -> levels are throughput-bound
// on a memory path, not latency-bound. Theory: per-XCD L2 capacity thrash (old
// 512-col tiles put ~4.3 MB of {input panel + edges + output writeback} on a 4 MB
// L2 for levels 2/3, pushing the 24x-reuse gather stream out to L3). This version
// narrows the per-XCD footprint: each wave gathers uint2 (8 B/lane x 64 lanes =
// 512 B/edge = 256 cols), and each level runs as TWO sequential half-col launches
// (cb4 = 0, then 512 uint2 = 2048 cols). grid.x = 8 keeps tile t -> XCD t pinning
// consistent across levels and launches, so h written on XCD t is re-gathered on
// XCD t from its own L2. Per-XCD per-launch budget (level 2): ~1 MB input panel +
// ~0.8 MB edges + ~0.8 MB output < 4 MB L2.
__global__ __launch_bounds__(256, 8)
void k_level(const int2* __restrict__ edges,   // pre-offset: level base * MAXDEG
             const int* __restrict__ cnt,      // pre-offset: level node base
             const uint2* __restrict__ nv,     // 1024 uint2 per node row (fp16 x4)
             uint2* __restrict__ outb,         // pre-offset row base (uint2 units)
             const int cb4) {                  // col base in uint2 units (0 or 512)
    const int lane = threadIdx.x & 63;
    const int wv   = threadIdx.x >> 6;
    // wave-uniform node id hoisted to SGPR: scalar edge/cnt addressing
    const int node = __builtin_amdgcn_readfirstlane((blockIdx.y << 2) | wv);
    const int col4 = cb4 + (blockIdx.x << 6) + lane;  // uint2 index in row, 0..1023

    int c = cnt[node];
    c = (c < 0) ? 0 : (c > MAXDEG ? MAXDEG : c);

    float a0 = 0.f, a1 = 0.f, a2 = 0.f, a3 = 0.f;

#define ACC4(q, W) {                                                    \
    const __half2 h0 = *(const __half2*)&(q).x;                         \
    const __half2 h1 = *(const __half2*)&(q).y;                         \
    a0 = fmaf(__low2float(h0),  (W), a0);                               \
    a1 = fmaf(__high2float(h0), (W), a1);                               \
    a2 = fmaf(__low2float(h1),  (W), a2);                               \
    a3 = fmaf(__high2float(h1), (W), a3); }

    for (int base = 0; base < c; base += 64) {
        // stage up to 64 edges of this wave's node into registers (always in-bounds)
        const int2 my = edges[(size_t)node * MAXDEG + base + lane];
        const int m = (c - base < 64) ? (c - base) : 64;
        int j = 0;
        for (; j + 4 <= m; j += 4) {
            const int   s0i = __builtin_amdgcn_readlane(my.x, j)     & 4095;
            const int   s1i = __builtin_amdgcn_readlane(my.x, j + 1) & 4095;
            const int   s2i = __builtin_amdgcn_readlane(my.x, j + 2) & 4095;
            const int   s3i = __builtin_amdgcn_readlane(my.x, j + 3) & 4095;
            const float wa  = __int_as_float(__builtin_amdgcn_readlane(my.y, j));
            const float wb  = __int_as_float(__builtin_amdgcn_readlane(my.y, j + 1));
            const float wc  = __int_as_float(__builtin_amdgcn_readlane(my.y, j + 2));
            const float wd  = __int_as_float(__builtin_amdgcn_readlane(my.y, j + 3));
            const uint2 q0 = nv[((size_t)s0i << 10) | col4];
            const uint2 q1 = nv[((size_t)s1i << 10) | col4];
            const uint2 q2 = nv[((size_t)s2i << 10) | col4];
            const uint2 q3 = nv[((size_t)s3i << 10) | col4];
            ACC4(q0, wa);
            ACC4(q1, wb);
            ACC4(q2, wc);
            ACC4(q3, wd);
        }
        for (; j < m; ++j) {
            const int   s0i = __builtin_amdgcn_readlane(my.x, j) & 4095;
            const float wa  = __int_as_float(__builtin_amdgcn_readlane(my.y, j));
            const uint2 q0 = nv[((size_t)s0i << 10) | col4];
            ACC4(q0, wa);
        }
    }
#undef ACC4

    a0 = fmaxf(a0, 0.f); a1 = fmaxf(a1, 0.f); a2 = fmaxf(a2, 0.f); a3 = fmaxf(a3, 0.f);

    const __half2 h0 = __floats2half2_rn(a0, a1);
    const __half2 h1 = __floats2half2_rn(a2, a3);
    uint2 p;
    p.x = *(const uint32_t*)&h0; p.y = *(const uint32_t*)&h1;
    outb[((size_t)node << 10) | col4] = p;
}

// ---------- out^T rows (fp16, [N_OUT][B]) -> d_out [B, N_OUT] fp32 ----------
__global__ __launch_bounds__(256) void k_transpose_out(const __half* __restrict__ outh,
                                                       float* __restrict__ out) {
    __shared__ float tile[32][33];
    const int tx = threadIdx.x, ty = threadIdx.y;   // 32 x 8
    const int n0 = blockIdx.x * 32;
    const int b0 = blockIdx.y * 32;
#pragma unroll
    for (int k = 0; k < 32; k += 8)
        tile[ty + k][tx] = __half2float(outh[(size_t)(n0 + ty + k) * BATCH + (b0 + tx)]);
    __syncthreads();
#pragma unroll
    for (int k = 0; k < 32; k += 8)
        out[(size_t)(b0 + ty + k) * N_OUT + (n0 + tx)] = tile[tx][ty + k];
}

extern "C" void kernel_launch(void* const* d_in, const int* in_sizes, int n_in,
                              void* d_out, int out_size, void* d_ws, size_t ws_size,
                              hipStream_t stream) {
    const float* x  = (const float*)d_in[0];
    const int* s0   = (const int*)d_in[1];
    const int* dd0  = (const int*)d_in[2];
    const float* w0 = (const float*)d_in[3];
    const int* s1   = (const int*)d_in[4];
    const int* dd1  = (const int*)d_in[5];
    const float* w1 = (const float*)d_in[6];
    const int* s2   = (const int*)d_in[7];
    const int* dd2  = (const int*)d_in[8];
    const float* w2 = (const float*)d_in[9];

    char* ws        = (char*)d_ws;
    uint2*    nv2   = (uint2*)ws;                    // fp16 node rows, 1024 uint2/row
    int2*     edges = (int2*)(ws + OFF_EDGES);
    int*      cnt   = (int*)(ws + OFF_CNT);

    // slotted edge build: memset + one massively-parallel fill (no scan)
    hipMemsetAsync(cnt, 0, NNODES * sizeof(int), stream);
    k_fill<<<ETOT / 256, 256, 0, stream>>>(s0, dd0, w0, s1, dd1, w1, s2, dd2, w2, cnt, edges);

    // x -> fp16 transposed node-value rows 0..511
    k_transpose_in<<<dim3(N_IN / 32, BATCH / 32), dim3(32, 8), 0, stream>>>(x, (__half*)ws);

    // levels: each level runs as two half-col launches (cb4 = 0, 512) to halve the
    // per-XCD L2 footprint; grid (8 col-tiles, H/4), 256 threads = 4 waves = 4 nodes.
    // Dependency chain is per-col-half: L1(cb) writes exactly the cols L2(cb) reads.
    for (int cb4 = 0; cb4 <= 512; cb4 += 512) {
        k_level<<<dim3(8, H1 / 4), 256, 0, stream>>>(edges, cnt, nv2,
                                                     nv2 + (size_t)N_IN * 1024, cb4);
    }
    for (int cb4 = 0; cb4 <= 512; cb4 += 512) {
        k_level<<<dim3(8, H2 / 4), 256, 0, stream>>>(edges + (size_t)H1 * MAXDEG, cnt + H1, nv2,
                                                     nv2 + (size_t)(N_IN + H1) * 1024, cb4);
    }
    for (int cb4 = 0; cb4 <= 512; cb4 += 512) {
        k_level<<<dim3(8, N_OUT / 4), 256, 0, stream>>>(edges + (size_t)(H1 + H2) * MAXDEG, cnt + H1 + H2, nv2,
                                                        nv2 + (size_t)(N_IN + H1 + H2) * 1024, cb4);
    }

    // out^T (fp16) -> d_out [B, N_OUT] fp32
    k_transpose_out<<<dim3(N_OUT / 32, BATCH / 32), dim3(32, 8), 0, stream>>>(
        (const __half*)(ws + (size_t)(N_IN + H1 + H2) * BATCH * 2), (float*)d_out);
}